// Round 2
// baseline (464.679 us; speedup 1.0000x reference)
//
#include <hip/hip_runtime.h>
#include <math.h>

// Problem constants
constexpr int D     = 2048;
constexpr int LAYER = 11;   // only the last layer's output survives the reference loop
constexpr int BATCH = 3;

// ---------------------------------------------------------------------------
// Kernel 1: fused LayerNorm + proj GEMV.
//   Each block re-computes LN(x) (3x2048) into LDS, then does 4 output rows
//   of z1[b,e] = xn[b,:] . proj_w[e,:] + proj_b[e]  (one wave per row).
// ---------------------------------------------------------------------------
__global__ __launch_bounds__(256) void k_ln_proj(const float* __restrict__ x,
                                                 const float* __restrict__ g,
                                                 const float* __restrict__ bt,
                                                 const float* __restrict__ W,
                                                 const float* __restrict__ bias,
                                                 float* __restrict__ z1) {
    const int tid  = threadIdx.x;
    const int wave = tid >> 6;
    const int lane = tid & 63;

    __shared__ float xn_s[BATCH * D];          // 24 KB
    __shared__ float wred[6][4];

    // ---- LayerNorm of the 3 rows (redundant per block; inputs L2-resident) ----
    float s0 = 0.f, s1 = 0.f, s2 = 0.f, q0 = 0.f, q1 = 0.f, q2 = 0.f;
    for (int i = tid; i < D; i += 256) {
        float v0 = x[0 * D + i], v1 = x[1 * D + i], v2 = x[2 * D + i];
        s0 += v0; q0 += v0 * v0;
        s1 += v1; q1 += v1 * v1;
        s2 += v2; q2 += v2 * v2;
    }
#pragma unroll
    for (int off = 32; off; off >>= 1) {
        s0 += __shfl_down(s0, off); q0 += __shfl_down(q0, off);
        s1 += __shfl_down(s1, off); q1 += __shfl_down(q1, off);
        s2 += __shfl_down(s2, off); q2 += __shfl_down(q2, off);
    }
    if (lane == 0) {
        wred[0][wave] = s0; wred[1][wave] = q0;
        wred[2][wave] = s1; wred[3][wave] = q1;
        wred[4][wave] = s2; wred[5][wave] = q2;
    }
    __syncthreads();
    const float S0 = wred[0][0] + wred[0][1] + wred[0][2] + wred[0][3];
    const float Q0 = wred[1][0] + wred[1][1] + wred[1][2] + wred[1][3];
    const float S1 = wred[2][0] + wred[2][1] + wred[2][2] + wred[2][3];
    const float Q1 = wred[3][0] + wred[3][1] + wred[3][2] + wred[3][3];
    const float S2 = wred[4][0] + wred[4][1] + wred[4][2] + wred[4][3];
    const float Q2 = wred[5][0] + wred[5][1] + wred[5][2] + wred[5][3];
    const float inv = 1.f / D;
    const float mu0 = S0 * inv, mu1 = S1 * inv, mu2 = S2 * inv;
    const float r0 = rsqrtf(Q0 * inv - mu0 * mu0 + 1e-5f);
    const float r1 = rsqrtf(Q1 * inv - mu1 * mu1 + 1e-5f);
    const float r2 = rsqrtf(Q2 * inv - mu2 * mu2 + 1e-5f);

    for (int i = tid; i < D; i += 256) {
        const float gi = g[i], bi = bt[i];
        xn_s[0 * D + i] = (x[0 * D + i] - mu0) * r0 * gi + bi;
        xn_s[1 * D + i] = (x[1 * D + i] - mu1) * r1 * gi + bi;
        xn_s[2 * D + i] = (x[2 * D + i] - mu2) * r2 * gi + bi;
    }
    __syncthreads();

    // ---- GEMV: one wave per output row ----
    const int row = blockIdx.x * 4 + wave;
    const float4* __restrict__ Wr  = (const float4*)(W + (size_t)row * D);
    const float4* __restrict__ in4 = (const float4*)xn_s;

    float a0 = 0.f, a1 = 0.f, a2 = 0.f;
#pragma unroll
    for (int k = 0; k < 8; ++k) {
        const int idx = k * 64 + lane;
        const float4 w  = Wr[idx];
        const float4 x0 = in4[idx];
        const float4 x1 = in4[512 + idx];
        const float4 x2 = in4[1024 + idx];
        a0 += w.x * x0.x + w.y * x0.y + w.z * x0.z + w.w * x0.w;
        a1 += w.x * x1.x + w.y * x1.y + w.z * x1.z + w.w * x1.w;
        a2 += w.x * x2.x + w.y * x2.y + w.z * x2.z + w.w * x2.w;
    }
#pragma unroll
    for (int off = 32; off; off >>= 1) {
        a0 += __shfl_down(a0, off);
        a1 += __shfl_down(a1, off);
        a2 += __shfl_down(a2, off);
    }
    if (lane == 0) {
        const float bs = bias[row];
        z1[0 * D + row] = a0 + bs;
        z1[1 * D + row] = a1 + bs;
        z1[2 * D + row] = a2 + bs;
    }
}

// ---------------------------------------------------------------------------
// Kernel 2: dual GEMV (fconv + bconv) from z1. 1024 blocks: first 512 do
// fconv rows, next 512 do bconv rows. One wave per output row.
// ---------------------------------------------------------------------------
__global__ __launch_bounds__(256) void k_gemv2(const float* __restrict__ in,
                                               const float* __restrict__ W0,
                                               const float* __restrict__ b0,
                                               float* __restrict__ o0,
                                               const float* __restrict__ W1,
                                               const float* __restrict__ b1,
                                               float* __restrict__ o1) {
    const int wave = threadIdx.x >> 6;
    const int lane = threadIdx.x & 63;
    const int m      = blockIdx.x >> 9;
    const int rowblk = blockIdx.x & 511;
    const int row    = rowblk * 4 + wave;

    const float* __restrict__ W    = (m == 0) ? W0 : W1;
    const float* __restrict__ bias = (m == 0) ? b0 : b1;
    float* __restrict__ out        = (m == 0) ? o0 : o1;

    const float4* __restrict__ Wr  = (const float4*)(W + (size_t)row * D);
    const float4* __restrict__ in4 = (const float4*)in;

    float a0 = 0.f, a1 = 0.f, a2 = 0.f;
#pragma unroll
    for (int k = 0; k < 8; ++k) {
        const int idx = k * 64 + lane;
        const float4 w  = Wr[idx];
        const float4 x0 = in4[idx];
        const float4 x1 = in4[512 + idx];
        const float4 x2 = in4[1024 + idx];
        a0 += w.x * x0.x + w.y * x0.y + w.z * x0.z + w.w * x0.w;
        a1 += w.x * x1.x + w.y * x1.y + w.z * x1.z + w.w * x1.w;
        a2 += w.x * x2.x + w.y * x2.y + w.z * x2.z + w.w * x2.w;
    }
#pragma unroll
    for (int off = 32; off; off >>= 1) {
        a0 += __shfl_down(a0, off);
        a1 += __shfl_down(a1, off);
        a2 += __shfl_down(a2, off);
    }
    if (lane == 0) {
        const float bs = bias[row];
        out[0 * D + row] = a0 + bs;
        out[1 * D + row] = a1 + bs;
        out[2 * D + row] = a2 + bs;
    }
}

// ---------------------------------------------------------------------------
// Kernel 3: fused dbc projection + SSM epilogue.
//   24 blocks = 3 batch rows x 8 chunks of 256 outputs. Each block recomputes
//   dbc[b] (64 outputs x 2 directions) from L2-resident f/bw and dbc_w, then
//   does the elementwise epilogue for its 256-wide chunk of e.
//
//   With seq-len 1 and h0 = 0:  y_dir = u * (delta_dir * (B_dir . C_dir) + Dp)
//   out = (y_f + y_b) * silu(z1) + x
// ---------------------------------------------------------------------------
__device__ __forceinline__ float softplus_f(float v) {
    return fmaxf(v, 0.f) + log1pf(expf(-fabsf(v)));
}

__global__ __launch_bounds__(256) void k_dbc_final(const float* __restrict__ x,
                                                   const float* __restrict__ z1,
                                                   const float* __restrict__ f,
                                                   const float* __restrict__ bw,
                                                   const float* __restrict__ dbcW,
                                                   const float* __restrict__ dtpW,
                                                   const float* __restrict__ dtpB,
                                                   const float* __restrict__ Dp,
                                                   float* __restrict__ out) {
    const int tid = threadIdx.x;
    const int blk = blockIdx.x;
    const int b   = blk >> 3;         // batch row
    const int e   = ((blk & 7) << 8) + tid;

    __shared__ float dbc_s[2][64];

    // ---- dbc: 64 rows x 2 dirs x 2 half-dots = 256 tasks, one per thread ----
    {
        const int row  = tid >> 2;
        const int dir  = (tid >> 1) & 1;
        const int half = tid & 1;
        const float* __restrict__ u = dir ? bw : f;
        const float4* __restrict__ Wr = (const float4*)(dbcW + (size_t)row * D + half * (D / 2));
        const float4* __restrict__ u4 = (const float4*)(u + (size_t)b * D + half * (D / 2));

        float4 acc = make_float4(0.f, 0.f, 0.f, 0.f);
#pragma unroll 8
        for (int k = 0; k < 256; ++k) {          // 1024 elements = 256 float4
            const float4 w = Wr[k];
            const float4 v = u4[k];
            acc.x += w.x * v.x;
            acc.y += w.y * v.y;
            acc.z += w.z * v.z;
            acc.w += w.w * v.w;
        }
        float a = (acc.x + acc.y) + (acc.z + acc.w);
        a += __shfl_xor(a, 1);                   // combine the two halves
        if (half == 0) dbc_s[dir][row] = a;
    }
    __syncthreads();

    // ---- per-batch scalars BC = B . C over n=16 ----
    float bcf = 0.f, bcb = 0.f;
#pragma unroll
    for (int n = 0; n < 16; ++n) {
        bcf += dbc_s[0][32 + n] * dbc_s[0][48 + n];
        bcb += dbc_s[1][32 + n] * dbc_s[1][48 + n];
    }

    // ---- delta = softplus(dbc[:32] . dtp_w[e,:] + dtp_b[e]) ----
    float df = dtpB[e], db = dtpB[e];
    const float* __restrict__ wr = dtpW + (size_t)e * 32;
#pragma unroll
    for (int r = 0; r < 32; ++r) {
        const float w = wr[r];
        df += dbc_s[0][r] * w;
        db += dbc_s[1][r] * w;
    }
    df = softplus_f(df);
    db = softplus_f(db);

    const float fe  = f[b * D + e];
    const float be  = bw[b * D + e];
    const float dpe = Dp[e];
    const float y   = fe * (df * bcf + dpe) + be * (db * bcb + dpe);

    const float z   = z1[b * D + e];
    const float sil = z / (1.f + expf(-z));

    out[b * D + e] = y * sil + x[b * D + e];
}

// ---------------------------------------------------------------------------
extern "C" void kernel_launch(void* const* d_in, const int* in_sizes, int n_in,
                              void* d_out, int out_size, void* d_ws, size_t ws_size,
                              hipStream_t stream) {
    const float* x       = (const float*)d_in[0];
    const float* norm_g  = (const float*)d_in[1]  + (size_t)LAYER * D;
    const float* norm_b  = (const float*)d_in[2]  + (size_t)LAYER * D;
    const float* proj_w  = (const float*)d_in[3]  + (size_t)LAYER * D * D;
    const float* proj_b  = (const float*)d_in[4]  + (size_t)LAYER * D;
    const float* fconv_w = (const float*)d_in[5]  + (size_t)LAYER * D * D;
    const float* fconv_b = (const float*)d_in[6]  + (size_t)LAYER * D;
    const float* bconv_w = (const float*)d_in[7]  + (size_t)LAYER * D * D;
    const float* bconv_b = (const float*)d_in[8]  + (size_t)LAYER * D;
    const float* dbc_w   = (const float*)d_in[9]  + (size_t)LAYER * 64 * D;
    const float* dtp_w   = (const float*)d_in[10] + (size_t)LAYER * D * 32;
    const float* dtp_b   = (const float*)d_in[11] + (size_t)LAYER * D;
    // d_in[12] = A_log: dead (seq-len 1, h0 = 0 -> dA never enters the output)
    const float* Dp      = (const float*)d_in[13] + (size_t)LAYER * D;

    float* out = (float*)d_out;

    float* ws  = (float*)d_ws;
    float* z1  = ws;             // 3*2048
    float* fv  = ws + 6144;      // 3*2048
    float* bwv = ws + 12288;     // 3*2048

    k_ln_proj<<<512, 256, 0, stream>>>(x, norm_g, norm_b, proj_w, proj_b, z1);
    k_gemv2<<<1024, 256, 0, stream>>>(z1, fconv_w, fconv_b, fv,
                                      bconv_w, bconv_b, bwv);
    k_dbc_final<<<24, 256, 0, stream>>>(x, z1, fv, bwv, dbc_w,
                                        dtp_w, dtp_b, Dp, out);
}